// Round 11
// baseline (193.217 us; speedup 1.0000x reference)
//
#include <hip/hip_runtime.h>
#include <hip/hip_bf16.h>

#define SS 8192
#define DD 2048
#define EE 64
#define CAP 128
// combine_weights size = SS*EE*CAP
#define SEC (67108864LL)

#define GATEB 512
#define FILLB 131072   // one 4KB chunk per block, rocclr-fill geometry

typedef float floatx4 __attribute__((ext_vector_type(4)));

__device__ __forceinline__ float bcast(float v, int lane) {
    return __builtin_bit_cast(float,
        __builtin_amdgcn_readlane(__builtin_bit_cast(int, v), lane));
}

// ---------------------------------------------------------------------------
// Kernel 1: fused {gate} + {zero-fill of 537 MB output}.
// Blocks 0..511       : gate FIRST (r7 A/B: gate-last serializes, +30us).
//                       Exact r5 readlane-broadcast gate.
// Blocks 512..131583  : fill, rocclr-mimic geometry -- each block writes ONE
//                       plain dwordx4 per thread (4 KB/block). The rocclr
//                       fill sustains 6.7 TB/s with this shape (1640
//                       blocks/us dispatch stream); our looped fills cap at
//                       3.3-4.3 TB/s. Single-variable test of the geometry.
// ---------------------------------------------------------------------------
__global__ __launch_bounds__(256) void k_fill_gate(const float* __restrict__ x,
                                                   const float* __restrict__ wg,
                                                   float* __restrict__ out,
                                                   int* __restrict__ idx_out,
                                                   float* __restrict__ gval_out,
                                                   float* __restrict__ gpart) {
    if (blockIdx.x >= GATEB) {
        const int fb = blockIdx.x - GATEB;  // 0..131071
        floatx4* __restrict__ out4 = (floatx4*)out;
        const floatx4 z = {0.f, 0.f, 0.f, 0.f};
        out4[(size_t)fb * 256 + threadIdx.x] = z;  // one plain dwordx4
        if (fb == 0 && threadIdx.x == 0) out[2 * SEC] = 0.f;  // tail element
        return;
    }

    // ---- gate path (exact r5) ----
    const int bid = blockIdx.x;  // 0..511
    const int lane = threadIdx.x & 63;
    const int wv = __builtin_amdgcn_readfirstlane(threadIdx.x >> 6); // 0..3
    const int tg = wv >> 1;   // token group within block
    const int dh = wv & 1;    // D half
    const int tokBase = bid * 16 + tg * 8;
    const float* xp = x + (size_t)tokBase * DD + dh * 1024;
    const float* wp = wg + (size_t)dh * 1024 * EE + lane;

    float acc[8] = {0.f, 0.f, 0.f, 0.f, 0.f, 0.f, 0.f, 0.f};

    for (int b = 0; b < 16; ++b) {
        float xv[8];
#pragma unroll
        for (int t = 0; t < 8; ++t)
            xv[t] = xp[(size_t)t * DD + b * 64 + lane];  // coalesced 256B

#pragma unroll
        for (int g = 0; g < 4; ++g) {
            float w[16];
#pragma unroll
            for (int j = 0; j < 16; ++j)
                w[j] = wp[(size_t)(b * 64 + g * 16 + j) * EE];  // coalesced
#pragma unroll
            for (int j = 0; j < 16; ++j) {
#pragma unroll
                for (int t = 0; t < 8; ++t)
                    acc[t] = fmaf(bcast(xv[t], g * 16 + j), w[j], acc[t]);
            }
        }
    }

    // combine the two D-halves through LDS
    __shared__ float part[4][8][64];
#pragma unroll
    for (int t = 0; t < 8; ++t) part[wv][t][lane] = acc[t];
    __syncthreads();

    __shared__ float gshare[2][64];
    if (dh == 0) {
        float gs = 0.f;
#pragma unroll
        for (int t = 0; t < 8; ++t) {
            float v = part[wv][t][lane] + part[wv + 1][t][lane];
            // argmax over lanes, first-index tie rule (matches jnp.argmax)
            float m = v;
            int mi = lane;
#pragma unroll
            for (int off = 1; off < 64; off <<= 1) {
                float ov = __shfl_xor(m, off);
                int oi = __shfl_xor(mi, off);
                if (ov > m || (ov == m && oi < mi)) { m = ov; mi = oi; }
            }
            float p = __expf(v - m);
            float s = p;
#pragma unroll
            for (int off = 1; off < 64; off <<= 1) s += __shfl_xor(s, off);
            gs += p / s;  // gates[tok][lane], accumulated per expert(=lane)
            if (lane == 0) {
                idx_out[tokBase + t] = mi;
                gval_out[tokBase + t] = 1.0f / s;  // gate value of argmax expert
            }
        }
        gshare[tg][lane] = gs;
    }
    __syncthreads();
    if (wv == 0) {
        gpart[(size_t)bid * 64 + lane] = gshare[0][lane] + gshare[1][lane];
    }
}

// ---------------------------------------------------------------------------
// Kernel 2: tail -- split-scan scatter + l_aux, one dispatch (r9).
// Blocks 0..63 (one per expert e): wave w scans tokens [2048w, 2048w+2048).
//   Phase 1: 32 independent coalesced idx loads, flags packed in a register,
//            wave count via shfl reduce. One __syncthreads for wave prefix.
//   Phase 2: 32-step ballot scan from register flags + scatter stores.
// Block 64: l_aux (idx histogram via LDS atomics + gpart reduction).
// ---------------------------------------------------------------------------
__global__ __launch_bounds__(256) void k_tail(const int* __restrict__ idx,
                                              const float* __restrict__ gval,
                                              const float* __restrict__ gpart,
                                              float* __restrict__ out) {
    const int tid = threadIdx.x;
    const int lane = tid & 63;
    const int wv = tid >> 6;

    if (blockIdx.x < 64) {
        const int e = blockIdx.x;
        const int sBase = wv * 2048;  // this wave's token segment

        unsigned int flags = 0;
#pragma unroll
        for (int c = 0; c < 32; ++c) {
            const int s = sBase + c * 64 + lane;
            if (idx[s] == e) flags |= (1u << c);
        }
        int mycount = __popc(flags);
#pragma unroll
        for (int off = 1; off < 64; off <<= 1)
            mycount += __shfl_xor(mycount, off);

        __shared__ int wc[4];
        if (lane == 0) wc[wv] = mycount;
        __syncthreads();
        int running = 0;
        for (int w2 = 0; w2 < wv; ++w2) running += wc[w2];

        for (int c = 0; c < 32; ++c) {
            const bool f = (flags >> c) & 1u;
            const unsigned long long mask = __ballot(f);
            const int rank = running + __popcll(mask & ((1ULL << lane) - 1ULL));
            if (f && rank < CAP) {
                const int s = sBase + c * 64 + lane;
                const size_t o = (size_t)s * (EE * CAP) + (size_t)e * CAP + rank;
                out[1 + o] = gval[s];                 // combine_weights
                out[1 + (size_t)SEC + o] = 1.0f;      // dispatch_mask
            }
            running += __popcll(mask);
        }
        return;
    }

    // ---- l_aux block (blockIdx.x == 64) ----
    __shared__ int hist[64];
    if (tid < 64) hist[tid] = 0;
    __syncthreads();
    for (int s = tid; s < SS; s += 256) atomicAdd(&hist[idx[s]], 1);
    __syncthreads();

    float sum = 0.f;
    for (int b = wv; b < 512; b += 4) sum += gpart[(size_t)b * 64 + lane];
    __shared__ float red[4][64];
    red[wv][lane] = sum;
    __syncthreads();
    if (tid < 64) {
        float gsum = red[0][lane] + red[1][lane] + red[2][lane] + red[3][lane];
        float term = gsum * (float)hist[lane];
#pragma unroll
        for (int off = 1; off < 64; off <<= 1) term += __shfl_xor(term, off);
        if (lane == 0)
            out[0] = term * ((float)EE / ((float)SS * (float)SS));
    }
}

extern "C" void kernel_launch(void* const* d_in, const int* in_sizes, int n_in,
                              void* d_out, int out_size, void* d_ws, size_t ws_size,
                              hipStream_t stream) {
    const float* x = (const float*)d_in[0];
    const float* wg = (const float*)d_in[1];
    float* out = (float*)d_out;

    // workspace layout (floats): idx[8192] | gval[8192] | gpart[512*64]
    int* idxp = (int*)d_ws;
    float* gval = (float*)d_ws + SS;
    float* gpart = (float*)d_ws + 2 * SS;

    // fused gate (blocks 0..511) + rocclr-geometry fill (blocks 512..131583)
    hipLaunchKernelGGL(k_fill_gate, dim3(GATEB + FILLB), dim3(256), 0, stream,
                       x, wg, out, idxp, gval, gpart);
    // split-scan scatter (blocks 0..63) + l_aux (block 64)
    hipLaunchKernelGGL(k_tail, dim3(65), dim3(256), 0, stream,
                       idxp, gval, gpart, out);
}